// Round 6
// baseline (291.025 us; speedup 1.0000x reference)
//
#include <hip/hip_runtime.h>

// Problem constants
#define BATCH 8
#define NQ    2048
#define NKV   2048
#define DIN   512
#define DKEY  512
#define DMOD  512

typedef __attribute__((ext_vector_type(8))) short bf16x8;
typedef __attribute__((ext_vector_type(4))) float f32x4;

__device__ __forceinline__ unsigned short f2bf(float f) {
  unsigned int u = __builtin_bit_cast(unsigned int, f);
  u += 0x7fffu + ((u >> 16) & 1u);   // RNE
  return (unsigned short)(u >> 16);
}

#define GLD16(gp, lp) __builtin_amdgcn_global_load_lds( \
    (const __attribute__((address_space(1))) unsigned int*)(gp), \
    (__attribute__((address_space(3))) unsigned int*)(lp), 16, 0, 0)

// ---------------------------------------------------------------------------
// Mask element-size detector: byte pos %4==1 nonzero <=> 1-byte bool elements.
__global__ void detect_mode(const unsigned int* __restrict__ mask, int* __restrict__ flag) {
  __shared__ int c1s;
  if (threadIdx.x == 0) c1s = 0;
  __syncthreads();
  int c1 = 0;
  for (int i = threadIdx.x; i < 16384; i += 256) {
    unsigned int u = mask[i];
    if (u & 0x0000ff00u) c1++;
  }
  atomicAdd(&c1s, c1);
  __syncthreads();
  if (threadIdx.x == 0) *flag = (c1s > 0) ? 1 : 4;  // element size in bytes
}

// ---------------------------------------------------------------------------
// Both activation converts in one launch.
__global__ void cvt_two(const float* __restrict__ a, const float* __restrict__ b,
                        unsigned short* __restrict__ oa, unsigned short* __restrict__ ob) {
  int i = blockIdx.x * 256 + threadIdx.x;
  const float* src;
  unsigned short* dst;
  int j;
  if (i < 2097152) { src = a; dst = oa; j = i; }
  else             { src = b; dst = ob; j = i - 2097152; }
  float4 v = ((const float4*)src)[j];
  ushort4 o;
  o.x = f2bf(v.x); o.y = f2bf(v.y); o.z = f2bf(v.z); o.w = f2bf(v.w);
  ((ushort4*)dst)[j] = o;
}

// All 3 weight transposes in one launch: Wt[n*512+k] = W[k*512+n]
__global__ void cvt_w3(const float* __restrict__ wq, const float* __restrict__ wk,
                       const float* __restrict__ wv,
                       unsigned short* __restrict__ oq, unsigned short* __restrict__ ok,
                       unsigned short* __restrict__ ov) {
  int idx = blockIdx.x * 256 + threadIdx.x;  // 0..786431
  int w = idx >> 18;
  int rem = idx & 262143;
  int n = rem >> 9, k = rem & 511;
  const float* W = (w == 0) ? wq : (w == 1) ? wk : wv;
  unsigned short* O = (w == 0) ? oq : (w == 1) ? ok : ov;
  O[n * 512 + k] = f2bf(W[k * 512 + n]);
}

// ---------------------------------------------------------------------------
// 256x256 tile, BK=64, 8-wave (4M x 2N), counted-vmcnt double-buffered GEMM.
// Used for projections (plain bf16 out) and scores (mask+scale+exp epilogue).
__device__ __forceinline__ void gemm256_core(
    const unsigned short* __restrict__ Ab,
    const unsigned short* __restrict__ Bb,
    unsigned short* __restrict__ C,
    long ldA, long ldB, long ldO, int nk, long bm, long bn, char* smem,
    // epilogue control: if emask != nullptr -> E = masked ? 0 : exp(x*SCALE)
    const unsigned char* emask, int esz, long maskBase)
{
  const int tid = threadIdx.x;
  const int lane = tid & 63;
  const int wid = tid >> 6;
  const int wr = wid >> 1;          // 0..3: wave's 64-row M quarter
  const int wc = wid & 1;           // 0..1: wave's 128-col N half
  const int fr = lane & 15, fq = lane >> 4;

  const int srow = tid >> 3;                 // 0..63 staging row within 64-row group
  const int clog = (tid & 7) ^ (srow & 7);   // pre-swizzled source chunk (involution)

  char* buf0 = smem;
  char* buf1 = smem + 65536;

  f32x4 acc[4][8] = {};

  const int swz0 = ((fq)     ^ (fr & 7)) * 16;   // kh=0 swizzled chunk byte
  const int swz1 = ((4 + fq) ^ (fr & 7)) * 16;   // kh=1
  const int arow = (wr * 64 + fr) * 128;         // A-frag byte base (mi=0)
  const int brow = (wc * 128 + fr) * 128;        // B-frag byte base (ni=0)

  // Prologue: stage tile 0 into buf0
  {
    const unsigned short* ga = Ab + (bm + srow) * ldA + clog * 8;
    const unsigned short* gb = Bb + (bn + srow) * ldB + clog * 8;
#pragma unroll
    for (int l = 0; l < 4; ++l) {
      GLD16(ga + (long)l * 64 * ldA, buf0 + l * 8192 + tid * 16);
      GLD16(gb + (long)l * 64 * ldB, buf0 + 32768 + l * 8192 + tid * 16);
    }
  }

  char* cur = buf0;
  char* nxt = buf1;
  for (int t = 0; t < nk; ++t) {
    __builtin_amdgcn_sched_barrier(0);
    __builtin_amdgcn_s_barrier();            // B1: prev tile's reads of nxt done
    if (t + 1 < nk) {
      const long k0 = (long)(t + 1) * 64;
      const unsigned short* ga = Ab + (bm + srow) * ldA + k0 + clog * 8;
      const unsigned short* gb = Bb + (bn + srow) * ldB + k0 + clog * 8;
#pragma unroll
      for (int l = 0; l < 4; ++l) {
        GLD16(ga + (long)l * 64 * ldA, nxt + l * 8192 + tid * 16);
        GLD16(gb + (long)l * 64 * ldB, nxt + 32768 + l * 8192 + tid * 16);
      }
      asm volatile("s_waitcnt vmcnt(8)" ::: "memory");  // drain tile t's 8, keep 8 in flight
    } else {
      asm volatile("s_waitcnt vmcnt(0)" ::: "memory");
    }
    __builtin_amdgcn_s_barrier();            // B2: tile t LDS complete for all waves
    __builtin_amdgcn_sched_barrier(0);

    const char* bufA = cur;
    const char* bufB = cur + 32768;
#pragma unroll
    for (int kh = 0; kh < 2; ++kh) {
      const int swz = kh ? swz1 : swz0;
      bf16x8 a[4];
#pragma unroll
      for (int mi = 0; mi < 4; ++mi)
        a[mi] = *(const bf16x8*)(bufA + arow + mi * 2048 + swz);
#pragma unroll
      for (int nh = 0; nh < 2; ++nh) {
        bf16x8 b[4];
#pragma unroll
        for (int nj = 0; nj < 4; ++nj)
          b[nj] = *(const bf16x8*)(bufB + brow + (nh * 4 + nj) * 2048 + swz);
        __builtin_amdgcn_s_setprio(1);
#pragma unroll
        for (int mi = 0; mi < 4; ++mi)
#pragma unroll
          for (int nj = 0; nj < 4; ++nj)
            acc[mi][nh * 4 + nj] = __builtin_amdgcn_mfma_f32_16x16x32_bf16(
                a[mi], b[nj], acc[mi][nh * 4 + nj], 0, 0, 0);
        __builtin_amdgcn_s_setprio(0);
      }
    }
    char* tmp = cur; cur = nxt; nxt = tmp;
  }

  // Epilogue: C/D layout col=lane&15, row=(lane>>4)*4+r  [m89-verified]
  const float SCALE = 0.04419417382415922f;  // 1/sqrt(512)
#pragma unroll
  for (int mi = 0; mi < 4; ++mi)
#pragma unroll
    for (int ni = 0; ni < 8; ++ni) {
      const long row = bm + wr * 64 + mi * 16 + fq * 4;
      const long col = bn + wc * 128 + ni * 16 + fr;
      if (emask == nullptr) {
#pragma unroll
        for (int r = 0; r < 4; ++r)
          C[(row + r) * ldO + col] = f2bf(acc[mi][ni][r]);
      } else {
#pragma unroll
        for (int r = 0; r < 4; ++r) {
          const long f = maskBase + (row + r) * ldO + col;
          bool msk;
          if (esz == 1) msk = emask[f] != 0;
          else          msk = ((const unsigned int*)emask)[f] != 0;
          float e = msk ? 0.0f : __expf(acc[mi][ni][r] * SCALE);
          C[(row + r) * ldO + col] = f2bf(e);
        }
      }
    }
}

// Scores: per batch E[2048x2048] = exp(mask(Q K^T)*scale), bf16
__global__ __launch_bounds__(512, 2) void gemm256_scores(
    const unsigned short* __restrict__ Q, const unsigned short* __restrict__ Kb,
    unsigned short* __restrict__ S,
    const unsigned char* __restrict__ mask, const int* __restrict__ flag)
{
  extern __shared__ char smem[];
  const long z = blockIdx.z;
  gemm256_core(Q + z * 1048576, Kb + z * 1048576, S + z * 4194304,
               512, 512, 2048, 8, (long)blockIdx.x * 256, (long)blockIdx.y * 256, smem,
               mask, *flag, z * 4194304);
}

// Projections, one launch, grid(64,2,3):
//  z=0: Q  = Xq*Wqt^T [16384x512];  z=1: K = Xn*Wkt^T;  z=2: Vt = Wvt*Xn^T [512x16384]
__global__ __launch_bounds__(512, 2) void gemm256_proj(
    const unsigned short* __restrict__ Xq, const unsigned short* __restrict__ Xn,
    const unsigned short* __restrict__ Wqt, const unsigned short* __restrict__ Wkt,
    const unsigned short* __restrict__ Wvt,
    unsigned short* __restrict__ Q, unsigned short* __restrict__ Kb,
    unsigned short* __restrict__ Vt)
{
  extern __shared__ char smem[];
  const int z = blockIdx.z;
  if (z == 0)
    gemm256_core(Xq, Wqt, Q, 512, 512, 512, 8,
                 (long)blockIdx.x * 256, (long)blockIdx.y * 256, smem, nullptr, 0, 0);
  else if (z == 1)
    gemm256_core(Xn, Wkt, Kb, 512, 512, 512, 8,
                 (long)blockIdx.x * 256, (long)blockIdx.y * 256, smem, nullptr, 0, 0);
  else
    gemm256_core(Wvt, Xn, Vt, 512, 512, 16384, 8,
                 (long)blockIdx.y * 256, (long)blockIdx.x * 256, smem, nullptr, 0, 0);
}

// ---------------------------------------------------------------------------
// Row sums of E -> inv_sum (f32). One wave per row, 4 rows per block.
__global__ __launch_bounds__(256) void rowsum_inv(
    const unsigned short* __restrict__ E, float* __restrict__ inv)
{
  const int row = blockIdx.x * 4 + (threadIdx.x >> 6);
  const int lane = threadIdx.x & 63;
  const uint4* p = (const uint4*)(E + (size_t)row * 2048);
  float s = 0.f;
#pragma unroll
  for (int j = 0; j < 4; ++j) {
    uint4 v = p[lane + j * 64];
    unsigned int w[4] = {v.x, v.y, v.z, v.w};
#pragma unroll
    for (int q = 0; q < 4; ++q) {
      s += __builtin_bit_cast(float, (w[q] & 0xffffu) << 16);
      s += __builtin_bit_cast(float, w[q] & 0xffff0000u);
    }
  }
#pragma unroll
  for (int off = 32; off > 0; off >>= 1) s += __shfl_xor(s, off);
  if (lane == 0) inv[row] = 1.0f / s;
}

// ---------------------------------------------------------------------------
// PV: per batch O[2048x512] = (E[2048x2048] @ V) * inv_sum, f32 out.
// BM=256 (q), BN=128 (d), BK=64 (n), nk=32. 8 waves 4Mx2N (64x64 per wave).
// LDS 96 KiB: per buffer A 32KB + B 16KB. Counted vmcnt(6).
__global__ __launch_bounds__(512, 2) void gemm_pv(
    const unsigned short* __restrict__ E, const unsigned short* __restrict__ Vt,
    const float* __restrict__ inv, float* __restrict__ O)
{
  extern __shared__ char smem[];
  const long z = blockIdx.z;
  const unsigned short* Ab = E + z * 4194304;        // ldA = 2048
  const unsigned short* Bb = Vt + z * 2048;          // ldB = 16384, rows = d
  const long bm = (long)blockIdx.x * 256;            // q
  const long bn = (long)blockIdx.y * 128;            // d

  const int tid = threadIdx.x;
  const int lane = tid & 63;
  const int wid = tid >> 6;
  const int wr = wid >> 1;           // 0..3: 64-row q quarter
  const int wc = wid & 1;            // 0..1: 64-col d half
  const int fr = lane & 15, fq = lane >> 4;

  const int srow = tid >> 3;
  const int clog = (tid & 7) ^ (srow & 7);

  char* buf0 = smem;                 // A 32KB | B 16KB
  char* buf1 = smem + 49152;

  f32x4 acc[4][4] = {};

  const int swz0 = ((fq)     ^ (fr & 7)) * 16;
  const int swz1 = ((4 + fq) ^ (fr & 7)) * 16;
  const int arow = (wr * 64 + fr) * 128;
  const int brow = (wc * 64 + fr) * 128;

  // Prologue: stage tile 0 (A: 4 passes, B: 2 passes = 6 loads/thread)
  {
    const unsigned short* ga = Ab + (bm + srow) * 2048 + clog * 8;
    const unsigned short* gb = Bb + (bn + srow) * 16384 + clog * 8;
#pragma unroll
    for (int l = 0; l < 4; ++l)
      GLD16(ga + (long)l * 64 * 2048, buf0 + l * 8192 + tid * 16);
#pragma unroll
    for (int l = 0; l < 2; ++l)
      GLD16(gb + (long)l * 64 * 16384, buf0 + 32768 + l * 8192 + tid * 16);
  }

  char* cur = buf0;
  char* nxt = buf1;
  for (int t = 0; t < 32; ++t) {
    __builtin_amdgcn_sched_barrier(0);
    __builtin_amdgcn_s_barrier();
    if (t + 1 < 32) {
      const long k0 = (long)(t + 1) * 64;
      const unsigned short* ga = Ab + (bm + srow) * 2048 + k0 + clog * 8;
      const unsigned short* gb = Bb + (bn + srow) * 16384 + k0 + clog * 8;
#pragma unroll
      for (int l = 0; l < 4; ++l)
        GLD16(ga + (long)l * 64 * 2048, nxt + l * 8192 + tid * 16);
#pragma unroll
      for (int l = 0; l < 2; ++l)
        GLD16(gb + (long)l * 64 * 16384, nxt + 32768 + l * 8192 + tid * 16);
      asm volatile("s_waitcnt vmcnt(6)" ::: "memory");
    } else {
      asm volatile("s_waitcnt vmcnt(0)" ::: "memory");
    }
    __builtin_amdgcn_s_barrier();
    __builtin_amdgcn_sched_barrier(0);

    const char* bufA = cur;
    const char* bufB = cur + 32768;
#pragma unroll
    for (int kh = 0; kh < 2; ++kh) {
      const int swz = kh ? swz1 : swz0;
      bf16x8 a[4], b[4];
#pragma unroll
      for (int mi = 0; mi < 4; ++mi)
        a[mi] = *(const bf16x8*)(bufA + arow + mi * 2048 + swz);
#pragma unroll
      for (int nj = 0; nj < 4; ++nj)
        b[nj] = *(const bf16x8*)(bufB + brow + nj * 2048 + swz);
      __builtin_amdgcn_s_setprio(1);
#pragma unroll
      for (int mi = 0; mi < 4; ++mi)
#pragma unroll
        for (int nj = 0; nj < 4; ++nj)
          acc[mi][nj] = __builtin_amdgcn_mfma_f32_16x16x32_bf16(
              a[mi], b[nj], acc[mi][nj], 0, 0, 0);
      __builtin_amdgcn_s_setprio(0);
    }
    char* tmp = cur; cur = nxt; nxt = tmp;
  }

  // Epilogue: O[q][d] = acc * inv_sum[q]
  float* Ob = O + z * 1048576;
  const float* invb = inv + z * 2048;
#pragma unroll
  for (int mi = 0; mi < 4; ++mi)
#pragma unroll
    for (int nj = 0; nj < 4; ++nj) {
      const long row = bm + wr * 64 + mi * 16 + fq * 4;
      const long col = bn + wc * 64 + nj * 16 + fr;
#pragma unroll
      for (int r = 0; r < 4; ++r)
        Ob[(row + r) * 512 + col] = acc[mi][nj][r] * invb[row + r];
    }
}

// ---------------------------------------------------------------------------
extern "C" void kernel_launch(void* const* d_in, const int* in_sizes, int n_in,
                              void* d_out, int out_size, void* d_ws, size_t ws_size,
                              hipStream_t stream) {
  const float* node  = (const float*)d_in[0];
  const float* query = (const float*)d_in[1];
  const unsigned char* mask = (const unsigned char*)d_in[2];
  const float* wq = (const float*)d_in[3];
  const float* wk = (const float*)d_in[4];
  const float* wv = (const float*)d_in[5];
  float* out = (float*)d_out;

  char* ws = (char*)d_ws;
  // ws layout: Q[0,16M) K[16M,32M) Vt[32M,48M) E[48M,112M)
  //            (Xq/Xn/Wt overlap E region, dead after proj)
  //            inv_sum f32[16384] @112M, flag @112M+64K
  unsigned short* Q   = (unsigned short*)(ws);
  unsigned short* Kb  = (unsigned short*)(ws + 16777216);
  unsigned short* Vt  = (unsigned short*)(ws + 33554432);
  unsigned short* E   = (unsigned short*)(ws + 50331648);
  unsigned short* Xq  = (unsigned short*)(ws + 50331648);
  unsigned short* Xn  = (unsigned short*)(ws + 50331648 + 16777216);
  unsigned short* Wqt = (unsigned short*)(ws + 50331648 + 33554432);
  unsigned short* Wkt = Wqt + 262144;
  unsigned short* Wvt = Wkt + 262144;
  float* inv = (float*)(ws + 117440512);
  int* flag  = (int*)(ws + 117440512 + 65536);

  detect_mode<<<1, 256, 0, stream>>>((const unsigned int*)mask, flag);

  cvt_two<<<16384, 256, 0, stream>>>(query, node, Xq, Xn);
  cvt_w3<<<3072, 256, 0, stream>>>(wq, wk, wv, Wqt, Wkt, Wvt);

  // Projections (one launch): Q, K, Vt
  dim3 gp(64, 2, 3);
  gemm256_proj<<<gp, 512, 131072, stream>>>(Xq, Xn, Wqt, Wkt, Wvt, Q, Kb, Vt);

  // Scores + mask + scale + exp: E = exp(mask(QK^T)*scale)  [bf16]
  dim3 gs(8, 8, 8);
  gemm256_scores<<<gs, 512, 131072, stream>>>(Q, Kb, E, mask, flag);

  // Row sums of E -> inverse
  rowsum_inv<<<4096, 256, 0, stream>>>(E, inv);

  // PV + normalize: O = (E @ V) * inv_sum
  dim3 gv(8, 4, 8);
  gemm_pv<<<gv, 512, 98304, stream>>>(E, Vt, inv, out);
}

// Round 7
// 219.689 us; speedup vs baseline: 1.3247x; 1.3247x over previous
//
#include <hip/hip_runtime.h>

// Problem constants
#define BATCH 8
#define NQ    2048
#define NKV   2048
#define DIN   512
#define DKEY  512
#define DMOD  512

typedef __attribute__((ext_vector_type(8))) short bf16x8;
typedef __attribute__((ext_vector_type(4))) float f32x4;

__device__ __forceinline__ unsigned short f2bf(float f) {
  unsigned int u = __builtin_bit_cast(unsigned int, f);
  u += 0x7fffu + ((u >> 16) & 1u);   // RNE
  return (unsigned short)(u >> 16);
}

#define GLD16(gp, lp) __builtin_amdgcn_global_load_lds( \
    (const __attribute__((address_space(1))) unsigned int*)(gp), \
    (__attribute__((address_space(3))) unsigned int*)(lp), 16, 0, 0)

// ---------------------------------------------------------------------------
// Mask element-size detector: byte pos %4==1 nonzero <=> 1-byte bool elements.
__global__ void detect_mode(const unsigned int* __restrict__ mask, int* __restrict__ flag) {
  __shared__ int c1s;
  if (threadIdx.x == 0) c1s = 0;
  __syncthreads();
  int c1 = 0;
  for (int i = threadIdx.x; i < 16384; i += 256) {
    unsigned int u = mask[i];
    if (u & 0x0000ff00u) c1++;
  }
  atomicAdd(&c1s, c1);
  __syncthreads();
  if (threadIdx.x == 0) *flag = (c1s > 0) ? 1 : 4;  // element size in bytes
}

// ---------------------------------------------------------------------------
// Pack mask into bits: pm[g] bit b = (mask[g*64+b] != 0). 524288 u64 words.
// Coalesced reads (64B or 256B contiguous per thread); absorbs the esz branch.
__global__ __launch_bounds__(256) void pack_mask(
    const unsigned char* __restrict__ m, const int* __restrict__ flag,
    unsigned long long* __restrict__ pm)
{
  const int g = blockIdx.x * 256 + threadIdx.x;  // 0..524287
  const size_t base = (size_t)g * 64;            // element offset
  unsigned long long bits = 0;
  if (*flag == 1) {
    const uint4* p = (const uint4*)(m + base);
#pragma unroll
    for (int j = 0; j < 4; ++j) {
      uint4 v = p[j];
      unsigned int w[4] = {v.x, v.y, v.z, v.w};
#pragma unroll
      for (int q = 0; q < 4; ++q) {
        unsigned int u = w[q];
#pragma unroll
        for (int b = 0; b < 4; ++b)
          if ((u >> (8 * b)) & 0xffu) bits |= 1ull << (j * 16 + q * 4 + b);
      }
    }
  } else {
    const uint4* p = (const uint4*)(m + base * 4);
#pragma unroll
    for (int j = 0; j < 16; ++j) {
      uint4 v = p[j];
      if (v.x) bits |= 1ull << (j * 4 + 0);
      if (v.y) bits |= 1ull << (j * 4 + 1);
      if (v.z) bits |= 1ull << (j * 4 + 2);
      if (v.w) bits |= 1ull << (j * 4 + 3);
    }
  }
  pm[g] = bits;
}

// ---------------------------------------------------------------------------
// Both activation converts in one launch.
__global__ void cvt_two(const float* __restrict__ a, const float* __restrict__ b,
                        unsigned short* __restrict__ oa, unsigned short* __restrict__ ob) {
  int i = blockIdx.x * 256 + threadIdx.x;
  const float* src;
  unsigned short* dst;
  int j;
  if (i < 2097152) { src = a; dst = oa; j = i; }
  else             { src = b; dst = ob; j = i - 2097152; }
  float4 v = ((const float4*)src)[j];
  ushort4 o;
  o.x = f2bf(v.x); o.y = f2bf(v.y); o.z = f2bf(v.z); o.w = f2bf(v.w);
  ((ushort4*)dst)[j] = o;
}

// All 3 weight transposes in one launch: Wt[n*512+k] = W[k*512+n]
__global__ void cvt_w3(const float* __restrict__ wq, const float* __restrict__ wk,
                       const float* __restrict__ wv,
                       unsigned short* __restrict__ oq, unsigned short* __restrict__ ok,
                       unsigned short* __restrict__ ov) {
  int idx = blockIdx.x * 256 + threadIdx.x;  // 0..786431
  int w = idx >> 18;
  int rem = idx & 262143;
  int n = rem >> 9, k = rem & 511;
  const float* W = (w == 0) ? wq : (w == 1) ? wk : wv;
  unsigned short* O = (w == 0) ? oq : (w == 1) ? ok : ov;
  O[n * 512 + k] = f2bf(W[k * 512 + n]);
}

// ---------------------------------------------------------------------------
// 256x256 tile, BK=64, 8-wave (4M x 2N), counted-vmcnt double-buffered GEMM.
// Used for projections (plain bf16 out) and scores (mask+scale+exp epilogue
// via packed bitmask: 2 broadcast u64 loads per output row).
__device__ __forceinline__ void gemm256_core(
    const unsigned short* __restrict__ Ab,
    const unsigned short* __restrict__ Bb,
    unsigned short* __restrict__ C,
    long ldA, long ldB, long ldO, int nk, long bm, long bn, char* smem,
    const unsigned long long* __restrict__ pmask)  // packed, batch-offset; null -> plain
{
  const int tid = threadIdx.x;
  const int lane = tid & 63;
  const int wid = tid >> 6;
  const int wr = wid >> 1;          // 0..3: wave's 64-row M quarter
  const int wc = wid & 1;           // 0..1: wave's 128-col N half
  const int fr = lane & 15, fq = lane >> 4;

  const int srow = tid >> 3;                 // 0..63 staging row within 64-row group
  const int clog = (tid & 7) ^ (srow & 7);   // pre-swizzled source chunk (involution)

  char* buf0 = smem;
  char* buf1 = smem + 65536;

  f32x4 acc[4][8] = {};

  const int swz0 = ((fq)     ^ (fr & 7)) * 16;   // kh=0 swizzled chunk byte
  const int swz1 = ((4 + fq) ^ (fr & 7)) * 16;   // kh=1
  const int arow = (wr * 64 + fr) * 128;         // A-frag byte base (mi=0)
  const int brow = (wc * 128 + fr) * 128;        // B-frag byte base (ni=0)

  // Prologue: stage tile 0 into buf0
  {
    const unsigned short* ga = Ab + (bm + srow) * ldA + clog * 8;
    const unsigned short* gb = Bb + (bn + srow) * ldB + clog * 8;
#pragma unroll
    for (int l = 0; l < 4; ++l) {
      GLD16(ga + (long)l * 64 * ldA, buf0 + l * 8192 + tid * 16);
      GLD16(gb + (long)l * 64 * ldB, buf0 + 32768 + l * 8192 + tid * 16);
    }
  }

  char* cur = buf0;
  char* nxt = buf1;
  for (int t = 0; t < nk; ++t) {
    __builtin_amdgcn_sched_barrier(0);
    __builtin_amdgcn_s_barrier();            // B1: prev tile's reads of nxt done
    if (t + 1 < nk) {
      const long k0 = (long)(t + 1) * 64;
      const unsigned short* ga = Ab + (bm + srow) * ldA + k0 + clog * 8;
      const unsigned short* gb = Bb + (bn + srow) * ldB + k0 + clog * 8;
#pragma unroll
      for (int l = 0; l < 4; ++l) {
        GLD16(ga + (long)l * 64 * ldA, nxt + l * 8192 + tid * 16);
        GLD16(gb + (long)l * 64 * ldB, nxt + 32768 + l * 8192 + tid * 16);
      }
      asm volatile("s_waitcnt vmcnt(8)" ::: "memory");  // drain tile t's 8, keep 8 in flight
    } else {
      asm volatile("s_waitcnt vmcnt(0)" ::: "memory");
    }
    __builtin_amdgcn_s_barrier();            // B2: tile t LDS complete for all waves
    __builtin_amdgcn_sched_barrier(0);

    const char* bufA = cur;
    const char* bufB = cur + 32768;
#pragma unroll
    for (int kh = 0; kh < 2; ++kh) {
      const int swz = kh ? swz1 : swz0;
      bf16x8 a[4];
#pragma unroll
      for (int mi = 0; mi < 4; ++mi)
        a[mi] = *(const bf16x8*)(bufA + arow + mi * 2048 + swz);
#pragma unroll
      for (int nh = 0; nh < 2; ++nh) {
        bf16x8 b[4];
#pragma unroll
        for (int nj = 0; nj < 4; ++nj)
          b[nj] = *(const bf16x8*)(bufB + brow + (nh * 4 + nj) * 2048 + swz);
        __builtin_amdgcn_s_setprio(1);
#pragma unroll
        for (int mi = 0; mi < 4; ++mi)
#pragma unroll
          for (int nj = 0; nj < 4; ++nj)
            acc[mi][nh * 4 + nj] = __builtin_amdgcn_mfma_f32_16x16x32_bf16(
                a[mi], b[nj], acc[mi][nh * 4 + nj], 0, 0, 0);
        __builtin_amdgcn_s_setprio(0);
      }
    }
    char* tmp = cur; cur = nxt; nxt = tmp;
  }

  // Epilogue: C/D layout col=lane&15, row=(lane>>4)*4+r  [m89-verified]
  const float SCALE = 0.04419417382415922f;  // 1/sqrt(512)
  if (pmask == nullptr) {
#pragma unroll
    for (int mi = 0; mi < 4; ++mi)
#pragma unroll
      for (int ni = 0; ni < 8; ++ni) {
        const long row = bm + wr * 64 + mi * 16 + fq * 4;
        const long col = bn + wc * 128 + ni * 16 + fr;
#pragma unroll
        for (int r = 0; r < 4; ++r)
          C[(row + r) * ldO + col] = f2bf(acc[mi][ni][r]);
      }
  } else {
    // E = masked ? 0 : exp(acc*SCALE). Mask bits: word (row*32 + col/64),
    // bit (col&63). Per row only 2 words needed (block col span 128/wave).
    const long wbase = (bn >> 6) + wc * 2;
#pragma unroll
    for (int mi = 0; mi < 4; ++mi) {
      const long rowb = bm + wr * 64 + mi * 16 + fq * 4;
#pragma unroll
      for (int r = 0; r < 4; ++r) {
        const long row = rowb + r;
        const unsigned long long w0 = pmask[row * 32 + wbase];
        const unsigned long long w1 = pmask[row * 32 + wbase + 1];
        unsigned short* Crow = C + row * ldO + bn + wc * 128 + fr;
#pragma unroll
        for (int ni = 0; ni < 8; ++ni) {
          const unsigned long long w = (ni < 4) ? w0 : w1;
          const int sh = (ni & 3) * 16 + fr;
          float e = ((w >> sh) & 1ull) ? 0.0f : __expf(acc[mi][ni][r] * SCALE);
          Crow[ni * 16] = f2bf(e);
        }
      }
    }
  }
}

// Scores: per batch E[2048x2048] = exp(mask(Q K^T)*scale), bf16
__global__ __launch_bounds__(512, 2) void gemm256_scores(
    const unsigned short* __restrict__ Q, const unsigned short* __restrict__ Kb,
    unsigned short* __restrict__ S, const unsigned long long* __restrict__ pm)
{
  extern __shared__ char smem[];
  const long z = blockIdx.z;
  gemm256_core(Q + z * 1048576, Kb + z * 1048576, S + z * 4194304,
               512, 512, 2048, 8, (long)blockIdx.x * 256, (long)blockIdx.y * 256, smem,
               pm + z * 65536);
}

// Projections, one launch, grid(64,2,3):
//  z=0: Q  = Xq*Wqt^T [16384x512];  z=1: K = Xn*Wkt^T;  z=2: Vt = Wvt*Xn^T [512x16384]
__global__ __launch_bounds__(512, 2) void gemm256_proj(
    const unsigned short* __restrict__ Xq, const unsigned short* __restrict__ Xn,
    const unsigned short* __restrict__ Wqt, const unsigned short* __restrict__ Wkt,
    const unsigned short* __restrict__ Wvt,
    unsigned short* __restrict__ Q, unsigned short* __restrict__ Kb,
    unsigned short* __restrict__ Vt)
{
  extern __shared__ char smem[];
  const int z = blockIdx.z;
  if (z == 0)
    gemm256_core(Xq, Wqt, Q, 512, 512, 512, 8,
                 (long)blockIdx.x * 256, (long)blockIdx.y * 256, smem, nullptr);
  else if (z == 1)
    gemm256_core(Xn, Wkt, Kb, 512, 512, 512, 8,
                 (long)blockIdx.x * 256, (long)blockIdx.y * 256, smem, nullptr);
  else
    gemm256_core(Wvt, Xn, Vt, 512, 512, 16384, 8,
                 (long)blockIdx.y * 256, (long)blockIdx.x * 256, smem, nullptr);
}

// ---------------------------------------------------------------------------
// Row sums of E -> inv_sum (f32). One wave per row, 4 rows per block.
__global__ __launch_bounds__(256) void rowsum_inv(
    const unsigned short* __restrict__ E, float* __restrict__ inv)
{
  const int row = blockIdx.x * 4 + (threadIdx.x >> 6);
  const int lane = threadIdx.x & 63;
  const uint4* p = (const uint4*)(E + (size_t)row * 2048);
  float s = 0.f;
#pragma unroll
  for (int j = 0; j < 4; ++j) {
    uint4 v = p[lane + j * 64];
    unsigned int w[4] = {v.x, v.y, v.z, v.w};
#pragma unroll
    for (int q = 0; q < 4; ++q) {
      s += __builtin_bit_cast(float, (w[q] & 0xffffu) << 16);
      s += __builtin_bit_cast(float, w[q] & 0xffff0000u);
    }
  }
#pragma unroll
  for (int off = 32; off > 0; off >>= 1) s += __shfl_xor(s, off);
  if (lane == 0) inv[row] = 1.0f / s;
}

// ---------------------------------------------------------------------------
// PV: per batch O[2048x512] = (E[2048x2048] @ V) * inv_sum, f32 out.
// BM=256 (q), BN=128 (d), BK=64 (n), nk=32. 8 waves 4Mx2N (64x64 per wave).
// LDS 96 KiB: per buffer A 32KB + B 16KB. Counted vmcnt(6).
__global__ __launch_bounds__(512, 2) void gemm_pv(
    const unsigned short* __restrict__ E, const unsigned short* __restrict__ Vt,
    const float* __restrict__ inv, float* __restrict__ O)
{
  extern __shared__ char smem[];
  const long z = blockIdx.z;
  const unsigned short* Ab = E + z * 4194304;        // ldA = 2048
  const unsigned short* Bb = Vt + z * 2048;          // ldB = 16384, rows = d
  const long bm = (long)blockIdx.x * 256;            // q
  const long bn = (long)blockIdx.y * 128;            // d

  const int tid = threadIdx.x;
  const int lane = tid & 63;
  const int wid = tid >> 6;
  const int wr = wid >> 1;           // 0..3: 64-row q quarter
  const int wc = wid & 1;            // 0..1: 64-col d half
  const int fr = lane & 15, fq = lane >> 4;

  const int srow = tid >> 3;
  const int clog = (tid & 7) ^ (srow & 7);

  char* buf0 = smem;                 // A 32KB | B 16KB
  char* buf1 = smem + 49152;

  f32x4 acc[4][4] = {};

  const int swz0 = ((fq)     ^ (fr & 7)) * 16;
  const int swz1 = ((4 + fq) ^ (fr & 7)) * 16;
  const int arow = (wr * 64 + fr) * 128;
  const int brow = (wc * 64 + fr) * 128;

  // Prologue: stage tile 0 (A: 4 passes, B: 2 passes = 6 loads/thread)
  {
    const unsigned short* ga = Ab + (bm + srow) * 2048 + clog * 8;
    const unsigned short* gb = Bb + (bn + srow) * 16384 + clog * 8;
#pragma unroll
    for (int l = 0; l < 4; ++l)
      GLD16(ga + (long)l * 64 * 2048, buf0 + l * 8192 + tid * 16);
#pragma unroll
    for (int l = 0; l < 2; ++l)
      GLD16(gb + (long)l * 64 * 16384, buf0 + 32768 + l * 8192 + tid * 16);
  }

  char* cur = buf0;
  char* nxt = buf1;
  for (int t = 0; t < 32; ++t) {
    __builtin_amdgcn_sched_barrier(0);
    __builtin_amdgcn_s_barrier();
    if (t + 1 < 32) {
      const long k0 = (long)(t + 1) * 64;
      const unsigned short* ga = Ab + (bm + srow) * 2048 + k0 + clog * 8;
      const unsigned short* gb = Bb + (bn + srow) * 16384 + k0 + clog * 8;
#pragma unroll
      for (int l = 0; l < 4; ++l)
        GLD16(ga + (long)l * 64 * 2048, nxt + l * 8192 + tid * 16);
#pragma unroll
      for (int l = 0; l < 2; ++l)
        GLD16(gb + (long)l * 64 * 16384, nxt + 32768 + l * 8192 + tid * 16);
      asm volatile("s_waitcnt vmcnt(6)" ::: "memory");
    } else {
      asm volatile("s_waitcnt vmcnt(0)" ::: "memory");
    }
    __builtin_amdgcn_s_barrier();
    __builtin_amdgcn_sched_barrier(0);

    const char* bufA = cur;
    const char* bufB = cur + 32768;
#pragma unroll
    for (int kh = 0; kh < 2; ++kh) {
      const int swz = kh ? swz1 : swz0;
      bf16x8 a[4], b[4];
#pragma unroll
      for (int mi = 0; mi < 4; ++mi)
        a[mi] = *(const bf16x8*)(bufA + arow + mi * 2048 + swz);
#pragma unroll
      for (int nj = 0; nj < 4; ++nj)
        b[nj] = *(const bf16x8*)(bufB + brow + nj * 2048 + swz);
      __builtin_amdgcn_s_setprio(1);
#pragma unroll
      for (int mi = 0; mi < 4; ++mi)
#pragma unroll
        for (int nj = 0; nj < 4; ++nj)
          acc[mi][nj] = __builtin_amdgcn_mfma_f32_16x16x32_bf16(
              a[mi], b[nj], acc[mi][nj], 0, 0, 0);
      __builtin_amdgcn_s_setprio(0);
    }
    char* tmp = cur; cur = nxt; nxt = tmp;
  }

  // Epilogue: O[q][d] = acc * inv_sum[q]
  float* Ob = O + z * 1048576;
  const float* invb = inv + z * 2048;
#pragma unroll
  for (int mi = 0; mi < 4; ++mi)
#pragma unroll
    for (int nj = 0; nj < 4; ++nj) {
      const long row = bm + wr * 64 + mi * 16 + fq * 4;
      const long col = bn + wc * 64 + nj * 16 + fr;
#pragma unroll
      for (int r = 0; r < 4; ++r)
        Ob[(row + r) * 512 + col] = acc[mi][nj][r] * invb[row + r];
    }
}

// ---------------------------------------------------------------------------
extern "C" void kernel_launch(void* const* d_in, const int* in_sizes, int n_in,
                              void* d_out, int out_size, void* d_ws, size_t ws_size,
                              hipStream_t stream) {
  const float* node  = (const float*)d_in[0];
  const float* query = (const float*)d_in[1];
  const unsigned char* mask = (const unsigned char*)d_in[2];
  const float* wq = (const float*)d_in[3];
  const float* wk = (const float*)d_in[4];
  const float* wv = (const float*)d_in[5];
  float* out = (float*)d_out;

  char* ws = (char*)d_ws;
  // ws layout: Q[0,16M) K[16M,32M) Vt[32M,48M) E[48M,112M)
  //            (Xq/Xn/Wt overlap E region, dead after proj)
  //            inv @112M (64KB), flag @112M+64K, packed mask @112M+1M (4MB)
  unsigned short* Q   = (unsigned short*)(ws);
  unsigned short* Kb  = (unsigned short*)(ws + 16777216);
  unsigned short* Vt  = (unsigned short*)(ws + 33554432);
  unsigned short* E   = (unsigned short*)(ws + 50331648);
  unsigned short* Xq  = (unsigned short*)(ws + 50331648);
  unsigned short* Xn  = (unsigned short*)(ws + 50331648 + 16777216);
  unsigned short* Wqt = (unsigned short*)(ws + 50331648 + 33554432);
  unsigned short* Wkt = Wqt + 262144;
  unsigned short* Wvt = Wkt + 262144;
  float* inv = (float*)(ws + 117440512);
  int* flag  = (int*)(ws + 117506048);
  unsigned long long* pm = (unsigned long long*)(ws + 118489088);

  detect_mode<<<1, 256, 0, stream>>>((const unsigned int*)mask, flag);
  pack_mask<<<2048, 256, 0, stream>>>(mask, flag, pm);

  cvt_two<<<16384, 256, 0, stream>>>(query, node, Xq, Xn);
  cvt_w3<<<3072, 256, 0, stream>>>(wq, wk, wv, Wqt, Wkt, Wvt);

  // Projections (one launch): Q, K, Vt
  dim3 gp(64, 2, 3);
  gemm256_proj<<<gp, 512, 131072, stream>>>(Xq, Xn, Wqt, Wkt, Wvt, Q, Kb, Vt);

  // Scores + mask + scale + exp: E = exp(mask(QK^T)*scale)  [bf16]
  dim3 gs(8, 8, 8);
  gemm256_scores<<<gs, 512, 131072, stream>>>(Q, Kb, E, pm);

  // Row sums of E -> inverse
  rowsum_inv<<<4096, 256, 0, stream>>>(E, inv);

  // PV + normalize: O = (E @ V) * inv_sum
  dim3 gv(8, 4, 8);
  gemm_pv<<<gv, 512, 98304, stream>>>(E, Vt, inv, out);
}

// Round 8
// 219.071 us; speedup vs baseline: 1.3284x; 1.0028x over previous
//
#include <hip/hip_runtime.h>

typedef __attribute__((ext_vector_type(8))) short bf16x8;
typedef __attribute__((ext_vector_type(4))) float f32x4;

__device__ __forceinline__ unsigned short f2bf(float f) {
  unsigned int u = __builtin_bit_cast(unsigned int, f);
  u += 0x7fffu + ((u >> 16) & 1u);   // RNE
  return (unsigned short)(u >> 16);
}

#define GLD16(gp, lp) __builtin_amdgcn_global_load_lds( \
    (const __attribute__((address_space(1))) unsigned int*)(gp), \
    (__attribute__((address_space(3))) unsigned int*)(lp), 16, 0, 0)

// ---------------------------------------------------------------------------
// Mask element-size detector: byte pos %4==1 nonzero <=> 1-byte bool elements.
__global__ void detect_mode(const unsigned int* __restrict__ mask, int* __restrict__ flag) {
  __shared__ int c1s;
  if (threadIdx.x == 0) c1s = 0;
  __syncthreads();
  int c1 = 0;
  for (int i = threadIdx.x; i < 16384; i += 256) {
    unsigned int u = mask[i];
    if (u & 0x0000ff00u) c1++;
  }
  atomicAdd(&c1s, c1);
  __syncthreads();
  if (threadIdx.x == 0) *flag = (c1s > 0) ? 1 : 4;  // element size in bytes
}

// ---------------------------------------------------------------------------
// Pack mask into bits: pm[g] bit b = (mask[g*64+b] != 0).
__global__ __launch_bounds__(256) void pack_mask(
    const unsigned char* __restrict__ m, const int* __restrict__ flag,
    unsigned long long* __restrict__ pm)
{
  const int g = blockIdx.x * 256 + threadIdx.x;  // 0..524287
  const size_t base = (size_t)g * 64;
  unsigned long long bits = 0;
  if (*flag == 1) {
    const uint4* p = (const uint4*)(m + base);
#pragma unroll
    for (int j = 0; j < 4; ++j) {
      uint4 v = p[j];
      unsigned int w[4] = {v.x, v.y, v.z, v.w};
#pragma unroll
      for (int q = 0; q < 4; ++q) {
        unsigned int u = w[q];
#pragma unroll
        for (int b = 0; b < 4; ++b)
          if ((u >> (8 * b)) & 0xffu) bits |= 1ull << (j * 16 + q * 4 + b);
      }
    }
  } else {
    const uint4* p = (const uint4*)(m + base * 4);
#pragma unroll
    for (int j = 0; j < 16; ++j) {
      uint4 v = p[j];
      if (v.x) bits |= 1ull << (j * 4 + 0);
      if (v.y) bits |= 1ull << (j * 4 + 1);
      if (v.z) bits |= 1ull << (j * 4 + 2);
      if (v.w) bits |= 1ull << (j * 4 + 3);
    }
  }
  pm[g] = bits;
}

// ---------------------------------------------------------------------------
__global__ void cvt_two(const float* __restrict__ a, const float* __restrict__ b,
                        unsigned short* __restrict__ oa, unsigned short* __restrict__ ob) {
  int i = blockIdx.x * 256 + threadIdx.x;
  const float* src;
  unsigned short* dst;
  int j;
  if (i < 2097152) { src = a; dst = oa; j = i; }
  else             { src = b; dst = ob; j = i - 2097152; }
  float4 v = ((const float4*)src)[j];
  ushort4 o;
  o.x = f2bf(v.x); o.y = f2bf(v.y); o.z = f2bf(v.z); o.w = f2bf(v.w);
  ((ushort4*)dst)[j] = o;
}

__global__ void cvt_w3(const float* __restrict__ wq, const float* __restrict__ wk,
                       const float* __restrict__ wv,
                       unsigned short* __restrict__ oq, unsigned short* __restrict__ ok,
                       unsigned short* __restrict__ ov) {
  int idx = blockIdx.x * 256 + threadIdx.x;  // 0..786431
  int w = idx >> 18;
  int rem = idx & 262143;
  int n = rem >> 9, k = rem & 511;
  const float* W = (w == 0) ? wq : (w == 1) ? wk : wv;
  unsigned short* O = (w == 0) ? oq : (w == 1) ? ok : ov;
  O[n * 512 + k] = f2bf(W[k * 512 + n]);
}

// ---------------------------------------------------------------------------
// Scores: 256x256 tile, BK=64, 8 waves (4M x 2N). Loop-top staging with
// counted vmcnt(8) (proven ledger), compute split into 4 phases
// {ds_read quadrant; barrier; setprio+16 MFMA; barrier} per K-tile.
// Epilogue: E = masked ? 0 : exp(acc*SCALE) (packed bitmask), bf16 write,
// + per-row partial sums reduced over 16 lanes -> atomicAdd(sums[row]).
__global__ __launch_bounds__(512, 1) void gemm256_scores(
    const unsigned short* __restrict__ Qg, const unsigned short* __restrict__ Kg,
    unsigned short* __restrict__ Sg, const unsigned long long* __restrict__ pm,
    float* __restrict__ sums)
{
  extern __shared__ char smem[];
  const long z = blockIdx.z;
  const unsigned short* Ab = Qg + z * 1048576;
  const unsigned short* Bb = Kg + z * 1048576;
  unsigned short* C = Sg + z * 4194304;
  const unsigned long long* pmask = pm + z * 65536;
  float* sumz = sums + z * 2048;
  const long bm = (long)blockIdx.x * 256;
  const long bn = (long)blockIdx.y * 256;

  const int tid = threadIdx.x;
  const int lane = tid & 63;
  const int wid = tid >> 6;
  const int wr = wid >> 1;           // 64-row M quarter
  const int wc = wid & 1;            // 128-col N half
  const int fr = lane & 15, fq = lane >> 4;
  const int srow = tid >> 3;
  const int clog = (tid & 7) ^ (srow & 7);

  char* buf0 = smem;
  char* buf1 = smem + 65536;

  f32x4 acc[4][8] = {};

  const int swz0 = ((fq)     ^ (fr & 7)) * 16;
  const int swz1 = ((4 + fq) ^ (fr & 7)) * 16;
  const int arow = (wr * 64 + fr) * 128;
  const int brow = (wc * 128 + fr) * 128;

  // Prologue: stage tile 0
  {
    const unsigned short* ga = Ab + (bm + srow) * 512 + clog * 8;
    const unsigned short* gb = Bb + (bn + srow) * 512 + clog * 8;
#pragma unroll
    for (int l = 0; l < 4; ++l) {
      GLD16(ga + (long)l * 64 * 512, buf0 + l * 8192 + tid * 16);
      GLD16(gb + (long)l * 64 * 512, buf0 + 32768 + l * 8192 + tid * 16);
    }
  }

  char* cur = buf0;
  char* nxt = buf1;
  for (int t = 0; t < 8; ++t) {
    __builtin_amdgcn_sched_barrier(0);
    __builtin_amdgcn_s_barrier();            // B1: prev reads of nxt done
    if (t < 7) {
      const long k0 = (long)(t + 1) * 64;
      const unsigned short* ga = Ab + (bm + srow) * 512 + k0 + clog * 8;
      const unsigned short* gb = Bb + (bn + srow) * 512 + k0 + clog * 8;
#pragma unroll
      for (int l = 0; l < 4; ++l) {
        GLD16(ga + (long)l * 64 * 512, nxt + l * 8192 + tid * 16);
        GLD16(gb + (long)l * 64 * 512, nxt + 32768 + l * 8192 + tid * 16);
      }
      asm volatile("s_waitcnt vmcnt(8)" ::: "memory");  // drain tile t, keep 8 in flight
    } else {
      asm volatile("s_waitcnt vmcnt(0)" ::: "memory");
    }
    __builtin_amdgcn_s_barrier();            // B2: tile t LDS ready
    __builtin_amdgcn_sched_barrier(0);

    const char* bufA = cur;
    const char* bufB = cur + 32768;
    // 4 phases: (kh, nh) quadrants, 16 MFMA each
#pragma unroll
    for (int kh = 0; kh < 2; ++kh) {
      const int swz = kh ? swz1 : swz0;
      bf16x8 a[4];
#pragma unroll
      for (int mi = 0; mi < 4; ++mi)
        a[mi] = *(const bf16x8*)(bufA + arow + mi * 2048 + swz);
#pragma unroll
      for (int nh = 0; nh < 2; ++nh) {
        bf16x8 b[4];
#pragma unroll
        for (int nj = 0; nj < 4; ++nj)
          b[nj] = *(const bf16x8*)(bufB + brow + (nh * 4 + nj) * 2048 + swz);
        __builtin_amdgcn_sched_barrier(0);
        __builtin_amdgcn_s_barrier();        // phase: reads issued by all waves
        __builtin_amdgcn_s_setprio(1);
#pragma unroll
        for (int mi = 0; mi < 4; ++mi)
#pragma unroll
          for (int nj = 0; nj < 4; ++nj)
            acc[mi][nh * 4 + nj] = __builtin_amdgcn_mfma_f32_16x16x32_bf16(
                a[mi], b[nj], acc[mi][nh * 4 + nj], 0, 0, 0);
        __builtin_amdgcn_s_setprio(0);
        __builtin_amdgcn_sched_barrier(0);
      }
    }
    char* tmp = cur; cur = nxt; nxt = tmp;
  }

  // Epilogue. C/D layout: col=lane&15, row=(lane>>4)*4+r
  const float SCALE = 0.04419417382415922f;  // 1/sqrt(512)
  const long wbase = (bn >> 6) + wc * 2;
#pragma unroll
  for (int mi = 0; mi < 4; ++mi) {
    const long rowb = bm + wr * 64 + mi * 16 + fq * 4;
#pragma unroll
    for (int r = 0; r < 4; ++r) {
      const long row = rowb + r;
      const unsigned long long w0 = pmask[row * 32 + wbase];
      const unsigned long long w1 = pmask[row * 32 + wbase + 1];
      unsigned short* Crow = C + row * 2048 + bn + wc * 128 + fr;
      float s = 0.f;
#pragma unroll
      for (int ni = 0; ni < 8; ++ni) {
        const unsigned long long w = (ni < 4) ? w0 : w1;
        const int sh = (ni & 3) * 16 + fr;
        float e = ((w >> sh) & 1ull) ? 0.0f : __expf(acc[mi][ni][r] * SCALE);
        s += e;
        Crow[ni * 16] = f2bf(e);
      }
      // reduce s across the 16 fr-lanes of this row
      s += __shfl_xor(s, 1); s += __shfl_xor(s, 2);
      s += __shfl_xor(s, 4); s += __shfl_xor(s, 8);
      if (fr == 0) atomicAdd(&sumz[row], s);
    }
  }
}

// ---------------------------------------------------------------------------
// Narrow core: BM=256, BN=128, BK=64, 8 waves (4M x 2N, 64x64 per wave).
// LDS 96 KiB (A 32K + B 16K per buffer). Counted vmcnt(6). 2 phases/K-tile.
// mode 0: bf16 C row-major.  mode 1: f32 C, multiply by 1/sums[row].
__device__ __forceinline__ void gemm_narrow_core(
    const unsigned short* __restrict__ Ab,
    const unsigned short* __restrict__ Bb,
    void* __restrict__ Cb,
    long ldA, long ldB, long ldO, int nk, long bm, long bn, char* smem,
    int mode, const float* __restrict__ sumz)
{
  const int tid = threadIdx.x;
  const int lane = tid & 63;
  const int wid = tid >> 6;
  const int wr = wid >> 1;           // 64-row M quarter
  const int wc = wid & 1;            // 64-col N half
  const int fr = lane & 15, fq = lane >> 4;
  const int srow = tid >> 3;
  const int clog = (tid & 7) ^ (srow & 7);

  char* buf0 = smem;
  char* buf1 = smem + 49152;

  f32x4 acc[4][4] = {};

  const int swz0 = ((fq)     ^ (fr & 7)) * 16;
  const int swz1 = ((4 + fq) ^ (fr & 7)) * 16;
  const int arow = (wr * 64 + fr) * 128;
  const int brow = (wc * 64 + fr) * 128;

  // Prologue: stage tile 0 (A 4 + B 2 loads/thread)
  {
    const unsigned short* ga = Ab + (bm + srow) * ldA + clog * 8;
    const unsigned short* gb = Bb + (bn + srow) * ldB + clog * 8;
#pragma unroll
    for (int l = 0; l < 4; ++l)
      GLD16(ga + (long)l * 64 * ldA, buf0 + l * 8192 + tid * 16);
#pragma unroll
    for (int l = 0; l < 2; ++l)
      GLD16(gb + (long)l * 64 * ldB, buf0 + 32768 + l * 8192 + tid * 16);
  }

  char* cur = buf0;
  char* nxt = buf1;
  for (int t = 0; t < nk; ++t) {
    __builtin_amdgcn_sched_barrier(0);
    __builtin_amdgcn_s_barrier();
    if (t + 1 < nk) {
      const long k0 = (long)(t + 1) * 64;
      const unsigned short* ga = Ab + (bm + srow) * ldA + k0 + clog * 8;
      const unsigned short* gb = Bb + (bn + srow) * ldB + k0 + clog * 8;
#pragma unroll
      for (int l = 0; l < 4; ++l)
        GLD16(ga + (long)l * 64 * ldA, nxt + l * 8192 + tid * 16);
#pragma unroll
      for (int l = 0; l < 2; ++l)
        GLD16(gb + (long)l * 64 * ldB, nxt + 32768 + l * 8192 + tid * 16);
      asm volatile("s_waitcnt vmcnt(6)" ::: "memory");
    } else {
      asm volatile("s_waitcnt vmcnt(0)" ::: "memory");
    }
    __builtin_amdgcn_s_barrier();
    __builtin_amdgcn_sched_barrier(0);

    const char* bufA = cur;
    const char* bufB = cur + 32768;
    // 2 phases: kh halves, 16 MFMA each
#pragma unroll
    for (int kh = 0; kh < 2; ++kh) {
      const int swz = kh ? swz1 : swz0;
      bf16x8 a[4], b[4];
#pragma unroll
      for (int mi = 0; mi < 4; ++mi)
        a[mi] = *(const bf16x8*)(bufA + arow + mi * 2048 + swz);
#pragma unroll
      for (int nj = 0; nj < 4; ++nj)
        b[nj] = *(const bf16x8*)(bufB + brow + nj * 2048 + swz);
      __builtin_amdgcn_sched_barrier(0);
      __builtin_amdgcn_s_barrier();          // phase: reads issued by all waves
      __builtin_amdgcn_s_setprio(1);
#pragma unroll
      for (int mi = 0; mi < 4; ++mi)
#pragma unroll
        for (int nj = 0; nj < 4; ++nj)
          acc[mi][nj] = __builtin_amdgcn_mfma_f32_16x16x32_bf16(
              a[mi], b[nj], acc[mi][nj], 0, 0, 0);
      __builtin_amdgcn_s_setprio(0);
      __builtin_amdgcn_sched_barrier(0);
    }
    char* tmp = cur; cur = nxt; nxt = tmp;
  }

  if (mode == 0) {
    unsigned short* C = (unsigned short*)Cb;
#pragma unroll
    for (int mi = 0; mi < 4; ++mi)
#pragma unroll
      for (int nj = 0; nj < 4; ++nj) {
        const long row = bm + wr * 64 + mi * 16 + fq * 4;
        const long col = bn + wc * 64 + nj * 16 + fr;
#pragma unroll
        for (int r = 0; r < 4; ++r)
          C[(row + r) * ldO + col] = f2bf(acc[mi][nj][r]);
      }
  } else {
    float* C = (float*)Cb;
#pragma unroll
    for (int mi = 0; mi < 4; ++mi) {
      const long rowb = bm + wr * 64 + mi * 16 + fq * 4;
#pragma unroll
      for (int r = 0; r < 4; ++r) {
        const long row = rowb + r;
        const float iv = 1.0f / sumz[row];
        const long colb = bn + wc * 64 + fr;
#pragma unroll
        for (int nj = 0; nj < 4; ++nj)
          C[row * ldO + colb + nj * 16] = acc[mi][nj][r] * iv;
      }
    }
  }
}

// Projections, grid(64,4,3):
//  z=0: Q = Xq*Wqt^T [16384x512]; z=1: K = Xn*Wkt^T; z=2: Vt = Wvt*Xn^T [512x16384]
__global__ __launch_bounds__(512, 1) void gemm_proj(
    const unsigned short* __restrict__ Xq, const unsigned short* __restrict__ Xn,
    const unsigned short* __restrict__ Wqt, const unsigned short* __restrict__ Wkt,
    const unsigned short* __restrict__ Wvt,
    unsigned short* __restrict__ Q, unsigned short* __restrict__ Kb,
    unsigned short* __restrict__ Vt)
{
  extern __shared__ char smem[];
  const int z = blockIdx.z;
  if (z == 0) {
    gemm_narrow_core(Xq, Wqt, Q, 512, 512, 512, 8,
                     (long)blockIdx.x * 256, (long)blockIdx.y * 128, smem, 0, nullptr);
  } else if (z == 1) {
    gemm_narrow_core(Xn, Wkt, Kb, 512, 512, 512, 8,
                     (long)blockIdx.x * 256, (long)blockIdx.y * 128, smem, 0, nullptr);
  } else {
    const int flat = blockIdx.x * 4 + blockIdx.y;     // 0..255
    gemm_narrow_core(Wvt, Xn, Vt, 512, 512, 16384, 8,
                     (long)(flat >> 7) * 256, (long)(flat & 127) * 128, smem, 0, nullptr);
  }
}

// PV: O[2048x512] = (E @ V) / rowsum, f32. grid(8,4,8), nk=32.
__global__ __launch_bounds__(512, 1) void gemm_pv(
    const unsigned short* __restrict__ E, const unsigned short* __restrict__ Vt,
    const float* __restrict__ sums, float* __restrict__ O)
{
  extern __shared__ char smem[];
  const long z = blockIdx.z;
  gemm_narrow_core(E + z * 4194304, Vt + z * 2048, O + z * 1048576,
                   2048, 16384, 512, 32,
                   (long)blockIdx.x * 256, (long)blockIdx.y * 128, smem,
                   1, sums + z * 2048);
}

// ---------------------------------------------------------------------------
extern "C" void kernel_launch(void* const* d_in, const int* in_sizes, int n_in,
                              void* d_out, int out_size, void* d_ws, size_t ws_size,
                              hipStream_t stream) {
  const float* node  = (const float*)d_in[0];
  const float* query = (const float*)d_in[1];
  const unsigned char* mask = (const unsigned char*)d_in[2];
  const float* wq = (const float*)d_in[3];
  const float* wk = (const float*)d_in[4];
  const float* wv = (const float*)d_in[5];
  float* out = (float*)d_out;

  char* ws = (char*)d_ws;
  // ws: Q[0,16M) K[16M,32M) Vt[32M,48M) E[48M,112M)
  //     (Xq/Xn/Wt overlap E, dead after proj)
  //     sums f32[8][2048] @112M (64KB), flag @112M+64K, packed mask @112M+1M
  unsigned short* Q   = (unsigned short*)(ws);
  unsigned short* Kb  = (unsigned short*)(ws + 16777216);
  unsigned short* Vt  = (unsigned short*)(ws + 33554432);
  unsigned short* E   = (unsigned short*)(ws + 50331648);
  unsigned short* Xq  = (unsigned short*)(ws + 50331648);
  unsigned short* Xn  = (unsigned short*)(ws + 50331648 + 16777216);
  unsigned short* Wqt = (unsigned short*)(ws + 50331648 + 33554432);
  unsigned short* Wkt = Wqt + 262144;
  unsigned short* Wvt = Wkt + 262144;
  float* sums = (float*)(ws + 117440512);
  int* flag   = (int*)(ws + 117506048);
  unsigned long long* pm = (unsigned long long*)(ws + 118489088);

  detect_mode<<<1, 256, 0, stream>>>((const unsigned int*)mask, flag);
  pack_mask<<<2048, 256, 0, stream>>>(mask, flag, pm);

  cvt_two<<<16384, 256, 0, stream>>>(query, node, Xq, Xn);
  cvt_w3<<<3072, 256, 0, stream>>>(wq, wk, wv, Wqt, Wkt, Wvt);

  // Projections: 768 blocks = 3 even rounds at 1 block/CU
  dim3 gp(64, 4, 3);
  gemm_proj<<<gp, 512, 98304, stream>>>(Xq, Xn, Wqt, Wkt, Wvt, Q, Kb, Vt);

  // Zero row-sum accumulators, then scores (+exp +mask +partial row sums)
  hipMemsetAsync(sums, 0, 65536, stream);
  dim3 gs(8, 8, 8);
  gemm256_scores<<<gs, 512, 131072, stream>>>(Q, Kb, E, pm, sums);

  // PV + normalize
  dim3 gv(8, 4, 8);
  gemm_pv<<<gv, 512, 98304, stream>>>(E, Vt, sums, out);
}